// Round 5
// baseline (152.719 us; speedup 1.0000x reference)
//
#include <hip/hip_runtime.h>
#include <hip/hip_bf16.h>

// Problem constants (NoiseEfficientNet): B=32, Cin=96, Cout=144, H=W=56, 3x3 pad1
#define B_    32
#define CIN   96
#define COUT  144
#define H_    56
#define W_    56
#define HW    3136      // 56*56
#define NPIX  100352    // 32*3136
#define KTOT  864       // 9 taps * 96 ci
#define MT    256       // workgroup pixel tile (8 waves x 32 pixels each)
#define TAPSZ (COUT*CIN) // 13824 shorts per tap in Wt
// padded input layout: [B][58][58][96] bf16, zero borders
#define W2    58
#define PLANE (W2*W2)   // 3364
#define XTP_SHORTS ((size_t)B_ * PLANE * CIN)  // 10,334,208

typedef short  short8  __attribute__((ext_vector_type(8)));
typedef float  floatx4 __attribute__((ext_vector_type(4)));

__device__ __forceinline__ unsigned short f2bf(float f) {
    union { float f; unsigned int u; } v; v.f = f;
    unsigned int u = v.u;
    return (unsigned short)((u + 0x7FFFu + ((u >> 16) & 1u)) >> 16);  // RNE
}

// async global->LDS, 16B per lane; LDS dest is wave-uniform base + lane*16
__device__ __forceinline__ void glds16(const void* g, void* l) {
    __builtin_amdgcn_global_load_lds(
        (const __attribute__((address_space(1))) unsigned int*)g,
        (__attribute__((address_space(3))) unsigned int*)l, 16, 0, 0);
}

// ---------------------------------------------------------------------------
// Fused prep kernel (identical to v5 — verified).
//   transpose: x [B][96][56][56] f32 -> xTp [B][58][58][96] bf16 (interior)
//   borders:   zero the 1-px halo ring of xTp
//   weights:   Wm [144][96][3][3] f32 -> Wt [tap][g][co][8] bf16
//   E table:   E [B][144][3][3] f32 (boundary-class constants, extra path)
// ---------------------------------------------------------------------------
#define TB 1568
#define WB 486
#define EB 18
#define ZB 342   // border-zero blocks: 342*256 short8 = 87552 = 32*2736 units
__global__ __launch_bounds__(256) void prep_all(const float* __restrict__ x,
                                                unsigned short* __restrict__ xTp,
                                                const float* __restrict__ Wm,
                                                unsigned short* __restrict__ Wt,
                                                const float* __restrict__ extra,
                                                const float* __restrict__ Wx,
                                                const float* __restrict__ bm,
                                                const float* __restrict__ bx,
                                                float* __restrict__ E) {
    __shared__ __align__(16) unsigned short tile[64][CIN + 8];
    int blk = blockIdx.x;
    int t = threadIdx.x;
    if (blk < TB) {
        int b   = blk / 49;
        int hw0 = (blk % 49) * 64;
        const float* xb = x + (size_t)b * CIN * HW;
        for (int i = t; i < CIN * 16; i += 256) {
            int ci = i >> 4, seg = i & 15;
            float4 v = *(const float4*)(xb + (size_t)ci * HW + hw0 + seg * 4);
            int hwl = seg * 4;
            tile[hwl + 0][ci] = f2bf(v.x);
            tile[hwl + 1][ci] = f2bf(v.y);
            tile[hwl + 2][ci] = f2bf(v.z);
            tile[hwl + 3][ci] = f2bf(v.w);
        }
        __syncthreads();
        int row = t >> 2, part = t & 3;
        int hw = hw0 + row;
        int h  = hw / W_;
        int w  = hw - h * W_;
        const uint4* s = (const uint4*)&tile[row][part * 24];
        uint4* d = (uint4*)(xTp + ((size_t)((b * W2 + h + 1) * W2 + (w + 1))) * CIN
                                + part * 24);
        d[0] = s[0]; d[1] = s[1]; d[2] = s[2];
    } else if (blk < TB + WB) {
        int i = (blk - TB) * 256 + t;      // [0, 124416)
        // Wt layout: [tap][g][co][e]  (13824 = 12*144*8 per tap, 1152 = 144*8)
        int tap = i / 13824;
        int r1  = i - tap * 13824;
        int g   = r1 / 1152;
        int r2  = r1 - g * 1152;
        int co  = r2 >> 3;
        int e   = r2 & 7;
        int ci  = g * 8 + e;
        Wt[i] = f2bf(Wm[((size_t)co * CIN + ci) * 9 + tap]);
    } else if (blk < TB + WB + EB) {
        int i = (blk - TB - WB) * 256 + t; // [0, 4608)
        int b = i / COUT, co = i - b * COUT;
        float base = bm[co] + bx[co];
        float m[3][3] = {{0,0,0},{0,0,0},{0,0,0}};
        for (int f = 0; f < 3; ++f) {
            float e = extra[(size_t)b * (COUT * 3) + co * 3 + f];
            const float* w = Wx + ((size_t)co * 3 + f) * 9;
            for (int rc = 0; rc < 3; ++rc) {
                int kh0 = (rc == 0) ? 1 : 0;
                int kh1 = (rc == 2) ? 1 : 2;
                for (int cc = 0; cc < 3; ++cc) {
                    int kw0 = (cc == 0) ? 1 : 0;
                    int kw1 = (cc == 2) ? 1 : 2;
                    float s = 0.f;
                    for (int kh = kh0; kh <= kh1; ++kh)
                        for (int kw = kw0; kw <= kw1; ++kw)
                            s += w[kh * 3 + kw];
                    m[rc][cc] += e * s;
                }
            }
        }
        float* dst = E + (size_t)i * 9;
        for (int rc = 0; rc < 3; ++rc)
            for (int cc = 0; cc < 3; ++cc)
                dst[rc * 3 + cc] = base + m[rc][cc];
    } else {
        // zero the halo ring: per image 2736 short8 units
        int i = (blk - TB - WB - EB) * 256 + t;   // [0, 87552)
        int b = i / 2736;
        int r = i - b * 2736;
        size_t base_b = (size_t)b * PLANE * CIN;
        size_t addr;
        if (r < 696) {
            addr = base_b + (size_t)r * 8;
        } else if (r < 1392) {
            addr = base_b + (size_t)57 * W2 * CIN + (size_t)(r - 696) * 8;
        } else if (r < 2064) {
            int r2 = r - 1392;
            int h = 1 + r2 / 12, u = r2 - (r2 / 12) * 12;
            addr = base_b + (size_t)(h * W2) * CIN + (size_t)u * 8;
        } else {
            int r2 = r - 2064;
            int h = 1 + r2 / 12, u = r2 - (r2 / 12) * 12;
            addr = base_b + (size_t)(h * W2 + 57) * CIN + (size_t)u * 8;
        }
        *(short8*)(xTp + addr) = (short8){0, 0, 0, 0, 0, 0, 0, 0};
    }
}

// ---------------------------------------------------------------------------
// Main implicit GEMM v6.
// Block: 512 thr = 8 waves; block tile 256 px x 144 co; WAVE tile 32 px x
// 144 co (acc[2][9] = 72 regs, was 144). Total unified regs ~140 << 256 ->
// __launch_bounds__(512,2) is trivially satisfiable: 8 waves/CU, 2/SIMD,
// co-wave fills ds_read/A-load latency holes.
// A fragments DOUBLE-buffered (aA/aB, 48 regs — now affordable): all
// next-tap A-loads issue at the TOP of the tap, so the implicit vmcnt(0)
// at the tap barrier finds them already landed (v5 issued the ks=2 reload
// right before the barrier -> full exposed memory latency every tap).
// Tap loop rolled x2 (even/odd macro bodies) so register indices stay static.
// Epilogue: direct stores from acc D-layout, 64B runs per co, L2-merged.
// ---------------------------------------------------------------------------
#define TAP_BODY(TAP, CUR, ACUR, ANXT, PF)                                        \
    do {                                                                          \
        if (PF) {                                                                 \
            const int tap2 = (TAP) + 1;                                           \
            const int r3   = tap2 / 3;                                            \
            const int dh2  = r3 - 1, dw2 = tap2 - r3 * 3 - 1;                     \
            const unsigned short* wsrc = Wt + tap2 * TAPSZ;                       \
            unsigned short* bd = Bs + (1 - (CUR)) * TAPSZ;                        \
            _Pragma("unroll")                                                     \
            for (int j = 0; j < 3; ++j)                                           \
                glds16(wsrc + (tid + j * 512) * 8,                                \
                       (void*)(bd + (tid + j * 512) * 8));                        \
            if (bTail)                                                            \
                glds16(wsrc + (1536 + tid) * 8, (void*)(bd + (1536 + tid) * 8));  \
            const unsigned short* bT = xTp + (ptrdiff_t)((dh2 * W2 + dw2) * CIN); \
            _Pragma("unroll")                                                     \
            for (int ms = 0; ms < 2; ++ms)                                        \
                _Pragma("unroll")                                                 \
                for (int ks = 0; ks < 3; ++ks)                                    \
                    ANXT[ms][ks] = *(const short8*)(bT + aOff[ms] + ks * 32);     \
        }                                                                         \
        const unsigned short* Bp = BpBase + (CUR) * TAPSZ;                        \
        _Pragma("unroll")                                                         \
        for (int ks = 0; ks < 3; ++ks) {                                          \
            _Pragma("unroll")                                                     \
            for (int n3 = 0; n3 < 3; ++n3) {                                      \
                short8 b0 = *(const short8*)(Bp + ks * 4608 + (n3 * 3 + 0) * 128);\
                short8 b1 = *(const short8*)(Bp + ks * 4608 + (n3 * 3 + 1) * 128);\
                short8 b2 = *(const short8*)(Bp + ks * 4608 + (n3 * 3 + 2) * 128);\
                _Pragma("unroll")                                                 \
                for (int ms = 0; ms < 2; ++ms)                                    \
                    acc[ms][n3 * 3 + 0] = __builtin_amdgcn_mfma_f32_16x16x32_bf16(\
                        ACUR[ms][ks], b0, acc[ms][n3 * 3 + 0], 0, 0, 0);          \
                _Pragma("unroll")                                                 \
                for (int ms = 0; ms < 2; ++ms)                                    \
                    acc[ms][n3 * 3 + 1] = __builtin_amdgcn_mfma_f32_16x16x32_bf16(\
                        ACUR[ms][ks], b1, acc[ms][n3 * 3 + 1], 0, 0, 0);          \
                _Pragma("unroll")                                                 \
                for (int ms = 0; ms < 2; ++ms)                                    \
                    acc[ms][n3 * 3 + 2] = __builtin_amdgcn_mfma_f32_16x16x32_bf16(\
                        ACUR[ms][ks], b2, acc[ms][n3 * 3 + 2], 0, 0, 0);          \
            }                                                                     \
        }                                                                         \
        if (PF) __syncthreads();                                                  \
    } while (0)

__global__ __launch_bounds__(512, 2) void conv_gemm(const unsigned short* __restrict__ xTp,
                                                    const unsigned short* __restrict__ Wt,
                                                    const float* __restrict__ E,
                                                    float* __restrict__ out) {
    __shared__ __align__(16) unsigned short Bs[2 * TAPSZ];   // 2 x 27648 B

    int tid = threadIdx.x;
    int wv = tid >> 6, lane = tid & 63;
    int r16 = lane & 15, q = lane >> 4;
    int pixBase = blockIdx.x * MT;

    floatx4 acc[2][9];
    #pragma unroll
    for (int m = 0; m < 2; ++m)
        #pragma unroll
        for (int n = 0; n < 9; ++n)
            acc[m][n] = (floatx4){0.f, 0.f, 0.f, 0.f};

    // ---- A addressing: per-lane voffset in shorts (tap-invariant) ----
    int aOff[2];
    #pragma unroll
    for (int ms = 0; ms < 2; ++ms) {
        int p = pixBase + wv * 32 + ms * 16 + r16;   // A-frag m = lane&15
        int b = p / HW;
        int hw = p - b * HW;
        int h = hw / W_;
        int w = hw - h * W_;
        aOff[ms] = ((b * W2 + h + 1) * W2 + (w + 1)) * CIN + q * 8;
    }

    const bool bTail = (tid < 192);   // slots [1536,1728) by waves 0-2

    // B-frag read base (shorts): addr(n,ks) = Bp + ks*4608 + n*128
    const unsigned short* BpBase = Bs + (q * COUT + r16) * 8;

    // ---- double-buffered A fragments ----
    short8 aA[2][3], aB[2][3];

    // ---- prologue: stage tap 0 (linear sources) + load tap 0 A into aA ----
    {
        const unsigned short* wsrc = Wt;
        #pragma unroll
        for (int j = 0; j < 3; ++j)
            glds16(wsrc + (tid + j * 512) * 8, (void*)(Bs + (tid + j * 512) * 8));
        if (bTail)
            glds16(wsrc + (1536 + tid) * 8, (void*)(Bs + (1536 + tid) * 8));
        const unsigned short* bT = xTp + (ptrdiff_t)((-1 * W2 - 1) * CIN); // dh=dw=-1
        #pragma unroll
        for (int ms = 0; ms < 2; ++ms)
            #pragma unroll
            for (int ks = 0; ks < 3; ++ks)
                aA[ms][ks] = *(const short8*)(bT + aOff[ms] + ks * 32);
    }
    __syncthreads();   // tap 0 B in LDS, A in regs

    // taps 0..7 as 4 even/odd pairs (rolled), tap 8 tail without prefetch
    #pragma unroll 1
    for (int t2 = 0; t2 < 4; ++t2) {
        const int tapE = 2 * t2;
        TAP_BODY(tapE,     0, aA, aB, true);
        TAP_BODY(tapE + 1, 1, aB, aA, true);
    }
    TAP_BODY(8, 0, aA, aB, false);

    // ---- epilogue: direct stores, out = acc + E[b][co][rc(h)][cc(w)] ----
    #pragma unroll
    for (int ms = 0; ms < 2; ++ms) {
        int p0 = pixBase + wv * 32 + ms * 16 + q * 4;  // D-layout row = q*4+reg
        int b  = p0 / HW;
        int hw0 = p0 - b * HW;                          // 4-aligned, no b straddle
        int h = hw0 / W_;
        int w0 = hw0 - h * W_;                          // 4-aligned, no row straddle
        int rc = (h == 0) ? 0 : ((h == H_ - 1) ? 2 : 1);
        int cc0 = (w0 == 0) ? 0 : ((w0 == W_ - 1) ? 2 : 1);
        int cc1 = (w0 + 1 == W_ - 1) ? 2 : 1;
        int cc2 = (w0 + 2 == W_ - 1) ? 2 : 1;
        int cc3 = (w0 + 3 == W_ - 1) ? 2 : 1;
        const float* Ebase = E + (size_t)b * COUT * 9 + rc * 3;
        float* outB = out + (size_t)b * COUT * HW + hw0;
        #pragma unroll
        for (int n = 0; n < 9; ++n) {
            int co = n * 16 + r16;                      // D-layout col = lane&15
            const float* Eb = Ebase + co * 9;
            float4 v;
            v.x = acc[ms][n][0] + Eb[cc0];
            v.y = acc[ms][n][1] + Eb[cc1];
            v.z = acc[ms][n][2] + Eb[cc2];
            v.w = acc[ms][n][3] + Eb[cc3];
            *(float4*)(outB + (size_t)co * HW) = v;
        }
    }
}

// ---------------------------------------------------------------------------
extern "C" void kernel_launch(void* const* d_in, const int* in_sizes, int n_in,
                              void* d_out, int out_size, void* d_ws, size_t ws_size,
                              hipStream_t stream) {
    const float* x     = (const float*)d_in[0];
    const float* extra = (const float*)d_in[1];
    const float* Wm    = (const float*)d_in[2];
    const float* bm    = (const float*)d_in[3];
    const float* Wx    = (const float*)d_in[4];
    const float* bx    = (const float*)d_in[5];
    float* out = (float*)d_out;

    const size_t XT_BYTES = XTP_SHORTS * 2;            // 20,668,416
    const size_t WT_BYTES = (size_t)COUT * KTOT * 2;   //    248,832
    const size_t E_BYTES  = (size_t)B_ * COUT * 9 * 4; //    165,888
    if (ws_size < XT_BYTES + WT_BYTES + E_BYTES) return;

    unsigned short* xTp = (unsigned short*)d_ws;
    unsigned short* Wt  = (unsigned short*)((char*)d_ws + XT_BYTES);
    float*          E   = (float*)((char*)d_ws + XT_BYTES + WT_BYTES);

    prep_all<<<TB + WB + EB + ZB, 256, 0, stream>>>(x, xTp, Wm, Wt, extra, Wx, bm, bx, E);
    conv_gemm<<<NPIX / MT, 512, 0, stream>>>(xTp, Wt, E, out);
}

// Round 6
// 152.076 us; speedup vs baseline: 1.0042x; 1.0042x over previous
//
#include <hip/hip_runtime.h>
#include <hip/hip_bf16.h>

// Problem constants (NoiseEfficientNet): B=32, Cin=96, Cout=144, H=W=56, 3x3 pad1
#define B_    32
#define CIN   96
#define COUT  144
#define H_    56
#define W_    56
#define HW    3136      // 56*56
#define NPIX  100352    // 32*3136
#define KTOT  864       // 9 taps * 96 ci
#define MT    512       // workgroup pixel tile (8 waves x 64 pixels each)
#define TAPSZ (COUT*CIN) // 13824 shorts per tap in Wt
// padded input layout: [B][58][58][96] bf16, zero borders
#define W2    58
#define PLANE (W2*W2)   // 3364
#define XTP_SHORTS ((size_t)B_ * PLANE * CIN)  // 10,334,208

typedef short  short8  __attribute__((ext_vector_type(8)));
typedef float  floatx4 __attribute__((ext_vector_type(4)));

__device__ __forceinline__ unsigned short f2bf(float f) {
    union { float f; unsigned int u; } v; v.f = f;
    unsigned int u = v.u;
    return (unsigned short)((u + 0x7FFFu + ((u >> 16) & 1u)) >> 16);  // RNE
}

// async global->LDS, 16B per lane; LDS dest is wave-uniform base + lane*16
__device__ __forceinline__ void glds16(const void* g, void* l) {
    __builtin_amdgcn_global_load_lds(
        (const __attribute__((address_space(1))) unsigned int*)g,
        (__attribute__((address_space(3))) unsigned int*)l, 16, 0, 0);
}

// ---------------------------------------------------------------------------
// Fused prep kernel (identical to v5/v6 — verified).
//   transpose: x [B][96][56][56] f32 -> xTp [B][58][58][96] bf16 (interior)
//   borders:   zero the 1-px halo ring of xTp
//   weights:   Wm [144][96][3][3] f32 -> Wt [tap][g][co][8] bf16
//   E table:   E [B][144][3][3] f32 (boundary-class constants, extra path)
// ---------------------------------------------------------------------------
#define TB 1568
#define WB 486
#define EB 18
#define ZB 342   // border-zero blocks: 342*256 short8 = 87552 = 32*2736 units
__global__ __launch_bounds__(256) void prep_all(const float* __restrict__ x,
                                                unsigned short* __restrict__ xTp,
                                                const float* __restrict__ Wm,
                                                unsigned short* __restrict__ Wt,
                                                const float* __restrict__ extra,
                                                const float* __restrict__ Wx,
                                                const float* __restrict__ bm,
                                                const float* __restrict__ bx,
                                                float* __restrict__ E) {
    __shared__ __align__(16) unsigned short tile[64][CIN + 8];
    int blk = blockIdx.x;
    int t = threadIdx.x;
    if (blk < TB) {
        int b   = blk / 49;
        int hw0 = (blk % 49) * 64;
        const float* xb = x + (size_t)b * CIN * HW;
        for (int i = t; i < CIN * 16; i += 256) {
            int ci = i >> 4, seg = i & 15;
            float4 v = *(const float4*)(xb + (size_t)ci * HW + hw0 + seg * 4);
            int hwl = seg * 4;
            tile[hwl + 0][ci] = f2bf(v.x);
            tile[hwl + 1][ci] = f2bf(v.y);
            tile[hwl + 2][ci] = f2bf(v.z);
            tile[hwl + 3][ci] = f2bf(v.w);
        }
        __syncthreads();
        int row = t >> 2, part = t & 3;
        int hw = hw0 + row;
        int h  = hw / W_;
        int w  = hw - h * W_;
        const uint4* s = (const uint4*)&tile[row][part * 24];
        uint4* d = (uint4*)(xTp + ((size_t)((b * W2 + h + 1) * W2 + (w + 1))) * CIN
                                + part * 24);
        d[0] = s[0]; d[1] = s[1]; d[2] = s[2];
    } else if (blk < TB + WB) {
        int i = (blk - TB) * 256 + t;      // [0, 124416)
        // Wt layout: [tap][g][co][e]  (13824 = 12*144*8 per tap, 1152 = 144*8)
        int tap = i / 13824;
        int r1  = i - tap * 13824;
        int g   = r1 / 1152;
        int r2  = r1 - g * 1152;
        int co  = r2 >> 3;
        int e   = r2 & 7;
        int ci  = g * 8 + e;
        Wt[i] = f2bf(Wm[((size_t)co * CIN + ci) * 9 + tap]);
    } else if (blk < TB + WB + EB) {
        int i = (blk - TB - WB) * 256 + t; // [0, 4608)
        int b = i / COUT, co = i - b * COUT;
        float base = bm[co] + bx[co];
        float m[3][3] = {{0,0,0},{0,0,0},{0,0,0}};
        for (int f = 0; f < 3; ++f) {
            float e = extra[(size_t)b * (COUT * 3) + co * 3 + f];
            const float* w = Wx + ((size_t)co * 3 + f) * 9;
            for (int rc = 0; rc < 3; ++rc) {
                int kh0 = (rc == 0) ? 1 : 0;
                int kh1 = (rc == 2) ? 1 : 2;
                for (int cc = 0; cc < 3; ++cc) {
                    int kw0 = (cc == 0) ? 1 : 0;
                    int kw1 = (cc == 2) ? 1 : 2;
                    float s = 0.f;
                    for (int kh = kh0; kh <= kh1; ++kh)
                        for (int kw = kw0; kw <= kw1; ++kw)
                            s += w[kh * 3 + kw];
                    m[rc][cc] += e * s;
                }
            }
        }
        float* dst = E + (size_t)i * 9;
        for (int rc = 0; rc < 3; ++rc)
            for (int cc = 0; cc < 3; ++cc)
                dst[rc * 3 + cc] = base + m[rc][cc];
    } else {
        // zero the halo ring: per image 2736 short8 units
        int i = (blk - TB - WB - EB) * 256 + t;   // [0, 87552)
        int b = i / 2736;
        int r = i - b * 2736;
        size_t base_b = (size_t)b * PLANE * CIN;
        size_t addr;
        if (r < 696) {
            addr = base_b + (size_t)r * 8;
        } else if (r < 1392) {
            addr = base_b + (size_t)57 * W2 * CIN + (size_t)(r - 696) * 8;
        } else if (r < 2064) {
            int r2 = r - 1392;
            int h = 1 + r2 / 12, u = r2 - (r2 / 12) * 12;
            addr = base_b + (size_t)(h * W2) * CIN + (size_t)u * 8;
        } else {
            int r2 = r - 2064;
            int h = 1 + r2 / 12, u = r2 - (r2 / 12) * 12;
            addr = base_b + (size_t)(h * W2 + 57) * CIN + (size_t)u * 8;
        }
        *(short8*)(xTp + addr) = (short8){0, 0, 0, 0, 0, 0, 0, 0};
    }
}

// ---------------------------------------------------------------------------
// Main implicit GEMM v7 — BARRIER-FREE tap streaming.
// The v2-v6 floor (~55us) was the 9 per-tap __syncthreads each with an
// implicit vmcnt(0)/lgkmcnt(0) full drain. v7 deletes them: weights are only
// 243 KB total, so stage taps 0-4 (138 KB) into LDS ONCE, compute 5 taps
// with no barriers at all (LDS read-only; A-loads are per-wave register
// loads), one barrier pair, re-stage taps 5-8 (110 KB), compute 4 taps.
// 3 barriers total instead of 9 full drains; waves slip freely.
// Block: 512 thr = 8 waves; wave tile 64 px x 144 co (ms=4: one ds_read_b128
// feeds 4 MFMAs — LDS pipe back under MFMA pipe). Block tile = 512 px.
// Grid = 196 blocks -> single round, all co-resident (138KB LDS = 1 blk/CU,
// 8 waves/CU, 2/SIMD). A rotating-prefetch single-buffer (48 regs); unified
// regs ~229 <= 256.
// Epilogue: direct stores from acc D-layout, 64B runs per co, L2-merged.
// ---------------------------------------------------------------------------
#define MFMA16(A, B, C) __builtin_amdgcn_mfma_f32_16x16x32_bf16(A, B, C, 0, 0, 0)

// one tap: 3 k-subtiles x (9 n x 4 ms) MFMAs from LDS tap slab BP;
// after subtile ks is consumed, rotate in next tap's a[*][ks] from BT.
#define TAP_COMPUTE(BP, BT, PF)                                                   \
    do {                                                                          \
        _Pragma("unroll")                                                         \
        for (int ks = 0; ks < 3; ++ks) {                                          \
            _Pragma("unroll")                                                     \
            for (int n3 = 0; n3 < 3; ++n3) {                                      \
                short8 b0 = *(const short8*)((BP) + ks * 4608 + (n3 * 3 + 0) * 128);\
                short8 b1 = *(const short8*)((BP) + ks * 4608 + (n3 * 3 + 1) * 128);\
                short8 b2 = *(const short8*)((BP) + ks * 4608 + (n3 * 3 + 2) * 128);\
                _Pragma("unroll")                                                 \
                for (int ms = 0; ms < 4; ++ms)                                    \
                    acc[ms][n3 * 3 + 0] = MFMA16(a[ms][ks], b0, acc[ms][n3 * 3 + 0]);\
                _Pragma("unroll")                                                 \
                for (int ms = 0; ms < 4; ++ms)                                    \
                    acc[ms][n3 * 3 + 1] = MFMA16(a[ms][ks], b1, acc[ms][n3 * 3 + 1]);\
                _Pragma("unroll")                                                 \
                for (int ms = 0; ms < 4; ++ms)                                    \
                    acc[ms][n3 * 3 + 2] = MFMA16(a[ms][ks], b2, acc[ms][n3 * 3 + 2]);\
            }                                                                     \
            if (PF) {                                                             \
                _Pragma("unroll")                                                 \
                for (int ms = 0; ms < 4; ++ms)                                    \
                    a[ms][ks] = *(const short8*)((BT) + aOff[ms] + ks * 32);      \
            }                                                                     \
        }                                                                         \
    } while (0)

__global__ __launch_bounds__(512, 2) void conv_gemm(const unsigned short* __restrict__ xTp,
                                                    const unsigned short* __restrict__ Wt,
                                                    const float* __restrict__ E,
                                                    float* __restrict__ out) {
    // 5 tap slabs of 13824 shorts each = 138,240 B (phase 2 reuses first 4)
    __shared__ __align__(16) unsigned short Bs[5 * TAPSZ];

    int tid = threadIdx.x;
    int wv = tid >> 6, lane = tid & 63;
    int r16 = lane & 15, q = lane >> 4;
    int pixBase = blockIdx.x * MT;

    floatx4 acc[4][9];
    #pragma unroll
    for (int m = 0; m < 4; ++m)
        #pragma unroll
        for (int n = 0; n < 9; ++n)
            acc[m][n] = (floatx4){0.f, 0.f, 0.f, 0.f};

    // ---- A addressing: per-lane voffset in shorts (tap-invariant) ----
    int aOff[4];
    #pragma unroll
    for (int ms = 0; ms < 4; ++ms) {
        int p = pixBase + wv * 64 + ms * 16 + r16;   // A-frag m = lane&15
        int b = p / HW;
        int hw = p - b * HW;
        int h = hw / W_;
        int w = hw - h * W_;
        aOff[ms] = ((b * W2 + h + 1) * W2 + (w + 1)) * CIN + q * 8;
    }

    // B-frag read base (shorts): addr(tapl,ks,n) = Bp + tapl*13824 + ks*4608 + n*128
    const unsigned short* BpBase = Bs + (q * COUT + r16) * 8;

    // ---- rotating A fragments ----
    short8 a[4][3];

    // ---- prologue: stage taps 0-4 (linear sources) + load tap-0 A ----
    {
        #pragma unroll
        for (int j = 0; j < 16; ++j)
            glds16(Wt + (tid + j * 512) * 8, (void*)(Bs + (tid + j * 512) * 8));
        if (tid < 448)   // tail: 448*16B -> total 138,240 B
            glds16(Wt + (tid + 16 * 512) * 8, (void*)(Bs + (tid + 16 * 512) * 8));
        const unsigned short* bT = xTp + (ptrdiff_t)((-1 * W2 - 1) * CIN); // tap0
        #pragma unroll
        for (int ms = 0; ms < 4; ++ms)
            #pragma unroll
            for (int ks = 0; ks < 3; ++ks)
                a[ms][ks] = *(const short8*)(bT + aOff[ms] + ks * 32);
    }
    __syncthreads();   // taps 0-4 in LDS, tap-0 A in regs

    // ---- phase 1: taps 0..4, zero barriers ----
    #pragma unroll 1
    for (int tap = 0; tap < 5; ++tap) {
        int t1 = tap + 1;                      // next tap (1..5) for A prefetch
        int r3 = (t1 * 11) >> 5;               // t1/3 for t1 in [0,9]
        const unsigned short* bT = xTp + (ptrdiff_t)(((r3 - 1) * W2 + (t1 - r3 * 3 - 1)) * CIN);
        const unsigned short* Bp = BpBase + tap * TAPSZ;
        TAP_COMPUTE(Bp, bT, true);
    }

    __syncthreads();   // all waves done reading taps 0-4
    // ---- re-stage taps 5-8 (110,592 B) into Bs[0..55296) ----
    {
        const unsigned short* wsrc = Wt + 5 * TAPSZ;
        #pragma unroll
        for (int j = 0; j < 13; ++j)
            glds16(wsrc + (tid + j * 512) * 8, (void*)(Bs + (tid + j * 512) * 8));
        if (tid < 256)   // tail: 256*16B -> total 110,592 B
            glds16(wsrc + (tid + 13 * 512) * 8, (void*)(Bs + (tid + 13 * 512) * 8));
    }
    __syncthreads();   // taps 5-8 in LDS (implicit vmcnt(0) drain)

    // ---- phase 2: taps 5..7 (prefetching), tap 8 peeled (no prefetch) ----
    #pragma unroll 1
    for (int tap = 5; tap < 8; ++tap) {
        int t1 = tap + 1;                      // 6..8
        int r3 = (t1 * 11) >> 5;
        const unsigned short* bT = xTp + (ptrdiff_t)(((r3 - 1) * W2 + (t1 - r3 * 3 - 1)) * CIN);
        const unsigned short* Bp = BpBase + (tap - 5) * TAPSZ;
        TAP_COMPUTE(Bp, bT, true);
    }
    {
        const unsigned short* Bp = BpBase + 3 * TAPSZ;
        TAP_COMPUTE(Bp, xTp, false);
    }

    // ---- epilogue: direct stores, out = acc + E[b][co][rc(h)][cc(w)] ----
    #pragma unroll
    for (int ms = 0; ms < 4; ++ms) {
        int p0 = pixBase + wv * 64 + ms * 16 + q * 4;  // D-layout row = q*4+reg
        int b  = p0 / HW;
        int hw0 = p0 - b * HW;                          // 4-aligned, no b straddle
        int h = hw0 / W_;
        int w0 = hw0 - h * W_;                          // 4-aligned, no row straddle
        int rc = (h == 0) ? 0 : ((h == H_ - 1) ? 2 : 1);
        int cc0 = (w0 == 0) ? 0 : ((w0 == W_ - 1) ? 2 : 1);
        int cc1 = (w0 + 1 == W_ - 1) ? 2 : 1;
        int cc2 = (w0 + 2 == W_ - 1) ? 2 : 1;
        int cc3 = (w0 + 3 == W_ - 1) ? 2 : 1;
        const float* Ebase = E + (size_t)b * COUT * 9 + rc * 3;
        float* outB = out + (size_t)b * COUT * HW + hw0;
        #pragma unroll
        for (int n = 0; n < 9; ++n) {
            int co = n * 16 + r16;                      // D-layout col = lane&15
            const float* Eb = Ebase + co * 9;
            float4 v;
            v.x = acc[ms][n][0] + Eb[cc0];
            v.y = acc[ms][n][1] + Eb[cc1];
            v.z = acc[ms][n][2] + Eb[cc2];
            v.w = acc[ms][n][3] + Eb[cc3];
            *(float4*)(outB + (size_t)co * HW) = v;
        }
    }
}

// ---------------------------------------------------------------------------
extern "C" void kernel_launch(void* const* d_in, const int* in_sizes, int n_in,
                              void* d_out, int out_size, void* d_ws, size_t ws_size,
                              hipStream_t stream) {
    const float* x     = (const float*)d_in[0];
    const float* extra = (const float*)d_in[1];
    const float* Wm    = (const float*)d_in[2];
    const float* bm    = (const float*)d_in[3];
    const float* Wx    = (const float*)d_in[4];
    const float* bx    = (const float*)d_in[5];
    float* out = (float*)d_out;

    const size_t XT_BYTES = XTP_SHORTS * 2;            // 20,668,416
    const size_t WT_BYTES = (size_t)COUT * KTOT * 2;   //    248,832
    const size_t E_BYTES  = (size_t)B_ * COUT * 9 * 4; //    165,888
    if (ws_size < XT_BYTES + WT_BYTES + E_BYTES) return;

    unsigned short* xTp = (unsigned short*)d_ws;
    unsigned short* Wt  = (unsigned short*)((char*)d_ws + XT_BYTES);
    float*          E   = (float*)((char*)d_ws + XT_BYTES + WT_BYTES);

    prep_all<<<TB + WB + EB + ZB, 256, 0, stream>>>(x, xTp, Wm, Wt, extra, Wx, bm, bx, E);
    conv_gemm<<<NPIX / MT, 512, 0, stream>>>(xTp, Wt, E, out);
}

// Round 7
// 150.144 us; speedup vs baseline: 1.0172x; 1.0129x over previous
//
#include <hip/hip_runtime.h>
#include <hip/hip_bf16.h>

// Problem constants (NoiseEfficientNet): B=32, Cin=96, Cout=144, H=W=56, 3x3 pad1
#define B_    32
#define CIN   96
#define COUT  144
#define H_    56
#define W_    56
#define HW    3136      // 56*56
#define NPIX  100352    // 32*3136
#define KTOT  864       // 9 taps * 96 ci
#define MT    128       // workgroup pixel tile (4 waves x 32 pixels each)
#define TAPSZ (COUT*CIN) // 13824 shorts per tap in Wt
// padded input layout: [B][58][58][96] bf16, zero borders
#define W2    58
#define PLANE (W2*W2)   // 3364
#define XTP_SHORTS ((size_t)B_ * PLANE * CIN)  // 10,334,208

typedef short  short8  __attribute__((ext_vector_type(8)));
typedef float  floatx4 __attribute__((ext_vector_type(4)));

__device__ __forceinline__ unsigned short f2bf(float f) {
    union { float f; unsigned int u; } v; v.f = f;
    unsigned int u = v.u;
    return (unsigned short)((u + 0x7FFFu + ((u >> 16) & 1u)) >> 16);  // RNE
}

// async global->LDS, 16B per lane; LDS dest is wave-uniform base + lane*16
__device__ __forceinline__ void glds16(const void* g, void* l) {
    __builtin_amdgcn_global_load_lds(
        (const __attribute__((address_space(1))) unsigned int*)g,
        (__attribute__((address_space(3))) unsigned int*)l, 16, 0, 0);
}

// ---------------------------------------------------------------------------
// Fused prep kernel (identical to v5/v6/v7 — verified).
//   transpose: x [B][96][56][56] f32 -> xTp [B][58][58][96] bf16 (interior)
//   borders:   zero the 1-px halo ring of xTp
//   weights:   Wm [144][96][3][3] f32 -> Wt [tap][g][co][8] bf16
//   E table:   E [B][144][3][3] f32 (boundary-class constants, extra path)
// ---------------------------------------------------------------------------
#define TB 1568
#define WB 486
#define EB 18
#define ZB 342   // border-zero blocks: 342*256 short8 = 87552 = 32*2736 units
__global__ __launch_bounds__(256) void prep_all(const float* __restrict__ x,
                                                unsigned short* __restrict__ xTp,
                                                const float* __restrict__ Wm,
                                                unsigned short* __restrict__ Wt,
                                                const float* __restrict__ extra,
                                                const float* __restrict__ Wx,
                                                const float* __restrict__ bm,
                                                const float* __restrict__ bx,
                                                float* __restrict__ E) {
    __shared__ __align__(16) unsigned short tile[64][CIN + 8];
    int blk = blockIdx.x;
    int t = threadIdx.x;
    if (blk < TB) {
        int b   = blk / 49;
        int hw0 = (blk % 49) * 64;
        const float* xb = x + (size_t)b * CIN * HW;
        for (int i = t; i < CIN * 16; i += 256) {
            int ci = i >> 4, seg = i & 15;
            float4 v = *(const float4*)(xb + (size_t)ci * HW + hw0 + seg * 4);
            int hwl = seg * 4;
            tile[hwl + 0][ci] = f2bf(v.x);
            tile[hwl + 1][ci] = f2bf(v.y);
            tile[hwl + 2][ci] = f2bf(v.z);
            tile[hwl + 3][ci] = f2bf(v.w);
        }
        __syncthreads();
        int row = t >> 2, part = t & 3;
        int hw = hw0 + row;
        int h  = hw / W_;
        int w  = hw - h * W_;
        const uint4* s = (const uint4*)&tile[row][part * 24];
        uint4* d = (uint4*)(xTp + ((size_t)((b * W2 + h + 1) * W2 + (w + 1))) * CIN
                                + part * 24);
        d[0] = s[0]; d[1] = s[1]; d[2] = s[2];
    } else if (blk < TB + WB) {
        int i = (blk - TB) * 256 + t;      // [0, 124416)
        // Wt layout: [tap][g][co][e]  (13824 = 12*144*8 per tap, 1152 = 144*8)
        int tap = i / 13824;
        int r1  = i - tap * 13824;
        int g   = r1 / 1152;
        int r2  = r1 - g * 1152;
        int co  = r2 >> 3;
        int e   = r2 & 7;
        int ci  = g * 8 + e;
        Wt[i] = f2bf(Wm[((size_t)co * CIN + ci) * 9 + tap]);
    } else if (blk < TB + WB + EB) {
        int i = (blk - TB - WB) * 256 + t; // [0, 4608)
        int b = i / COUT, co = i - b * COUT;
        float base = bm[co] + bx[co];
        float m[3][3] = {{0,0,0},{0,0,0},{0,0,0}};
        for (int f = 0; f < 3; ++f) {
            float e = extra[(size_t)b * (COUT * 3) + co * 3 + f];
            const float* w = Wx + ((size_t)co * 3 + f) * 9;
            for (int rc = 0; rc < 3; ++rc) {
                int kh0 = (rc == 0) ? 1 : 0;
                int kh1 = (rc == 2) ? 1 : 2;
                for (int cc = 0; cc < 3; ++cc) {
                    int kw0 = (cc == 0) ? 1 : 0;
                    int kw1 = (cc == 2) ? 1 : 2;
                    float s = 0.f;
                    for (int kh = kh0; kh <= kh1; ++kh)
                        for (int kw = kw0; kw <= kw1; ++kw)
                            s += w[kh * 3 + kw];
                    m[rc][cc] += e * s;
                }
            }
        }
        float* dst = E + (size_t)i * 9;
        for (int rc = 0; rc < 3; ++rc)
            for (int cc = 0; cc < 3; ++cc)
                dst[rc * 3 + cc] = base + m[rc][cc];
    } else {
        // zero the halo ring: per image 2736 short8 units
        int i = (blk - TB - WB - EB) * 256 + t;   // [0, 87552)
        int b = i / 2736;
        int r = i - b * 2736;
        size_t base_b = (size_t)b * PLANE * CIN;
        size_t addr;
        if (r < 696) {
            addr = base_b + (size_t)r * 8;
        } else if (r < 1392) {
            addr = base_b + (size_t)57 * W2 * CIN + (size_t)(r - 696) * 8;
        } else if (r < 2064) {
            int r2 = r - 1392;
            int h = 1 + r2 / 12, u = r2 - (r2 / 12) * 12;
            addr = base_b + (size_t)(h * W2) * CIN + (size_t)u * 8;
        } else {
            int r2 = r - 2064;
            int h = 1 + r2 / 12, u = r2 - (r2 / 12) * 12;
            addr = base_b + (size_t)(h * W2 + 57) * CIN + (size_t)u * 8;
        }
        *(short8*)(xTp + addr) = (short8){0, 0, 0, 0, 0, 0, 0, 0};
    }
}

// ---------------------------------------------------------------------------
// Main implicit GEMM v8 — max block-level TLP.
// v2-v7 lesson: floor is insensitive to barriers/staging/buffering; the only
// thing that moved it was waves/CU (4 -> 8 gave 66 -> 55). v8 pushes the TLP
// lever properly: 256-thr blocks (4 waves), wave tile 32 px x 144 co
// (acc[2][9]=72; + rotating a[2][3]=24 + B 12 + addr => ~125 unified regs,
// 3 waves/SIMD allowed), single-tap LDS buffer (27.6 KB). Grid = 784 blocks
// -> 3 blocks/CU co-resident (12 waves/CU), every CU busy. Per-tap
// stage+barrier drains are covered by the other 2-3 INDEPENDENT blocks
// slipping on the same CU — the mechanism every earlier version lacked.
// Epilogue: direct stores from acc D-layout, 64B runs per co, L2-merged.
// ---------------------------------------------------------------------------
#define MFMA16(A, B, C) __builtin_amdgcn_mfma_f32_16x16x32_bf16(A, B, C, 0, 0, 0)

__global__ __launch_bounds__(256, 3) void conv_gemm(const unsigned short* __restrict__ xTp,
                                                    const unsigned short* __restrict__ Wt,
                                                    const float* __restrict__ E,
                                                    float* __restrict__ out) {
    __shared__ __align__(16) unsigned short Bs[TAPSZ];   // 27,648 B, single tap

    int tid = threadIdx.x;
    int wv = tid >> 6, lane = tid & 63;
    int r16 = lane & 15, q = lane >> 4;
    int pixBase = blockIdx.x * MT;

    floatx4 acc[2][9];
    #pragma unroll
    for (int m = 0; m < 2; ++m)
        #pragma unroll
        for (int n = 0; n < 9; ++n)
            acc[m][n] = (floatx4){0.f, 0.f, 0.f, 0.f};

    // ---- A addressing: per-lane voffset in shorts (tap-invariant) ----
    int aOff[2];
    #pragma unroll
    for (int ms = 0; ms < 2; ++ms) {
        int p = pixBase + wv * 32 + ms * 16 + r16;   // A-frag m = lane&15
        int b = p / HW;
        int hw = p - b * HW;
        int h = hw / W_;
        int w = hw - h * W_;
        aOff[ms] = ((b * W2 + h + 1) * W2 + (w + 1)) * CIN + q * 8;
    }

    const bool bTail = (tid < 192);   // staging slots [1536,1728)

    // B-frag read base (shorts): addr(ks,n) = BpBase + ks*4608 + n*128
    const unsigned short* BpBase = Bs + (q * COUT + r16) * 8;

    // ---- rotating A fragments (single-buffered) ----
    short8 a[2][3];

    // ---- prologue: load tap-0 A ----
    {
        const unsigned short* bT = xTp - (ptrdiff_t)((W2 + 1) * CIN);  // dh=dw=-1
        #pragma unroll
        for (int ms = 0; ms < 2; ++ms)
            #pragma unroll
            for (int ks = 0; ks < 3; ++ks)
                a[ms][ks] = *(const short8*)(bT + aOff[ms] + ks * 32);
    }

    #pragma unroll 1
    for (int tap = 0; tap < 9; ++tap) {
        // ---- stage this tap's B into the single LDS buffer ----
        const unsigned short* wsrc = Wt + tap * TAPSZ;
        #pragma unroll
        for (int j = 0; j < 6; ++j)
            glds16(wsrc + (tid + j * 256) * 8, (void*)(Bs + (tid + j * 256) * 8));
        if (bTail)
            glds16(wsrc + (1536 + tid) * 8, (void*)(Bs + (1536 + tid) * 8));
        __syncthreads();   // B ready (implicit vmcnt(0) drains glds)

        // next-tap A base (clamped: last tap re-loads its own A, dead but cheap)
        const int t1 = (tap < 8) ? tap + 1 : 8;
        const int r3 = (t1 * 11) >> 5;               // t1/3 for t1 in [0,9]
        const unsigned short* bT =
            xTp + (ptrdiff_t)(((r3 - 1) * W2 + (t1 - r3 * 3 - 1)) * CIN);

        // ---- compute tap: 3 k-subtiles x (9 n x 2 ms) MFMAs; after phase ks
        //      consumes a[*][ks], rotate in next tap's fragment ----
        #pragma unroll
        for (int ks = 0; ks < 3; ++ks) {
            #pragma unroll
            for (int n3 = 0; n3 < 3; ++n3) {
                short8 b0 = *(const short8*)(BpBase + ks * 4608 + (n3 * 3 + 0) * 128);
                short8 b1 = *(const short8*)(BpBase + ks * 4608 + (n3 * 3 + 1) * 128);
                short8 b2 = *(const short8*)(BpBase + ks * 4608 + (n3 * 3 + 2) * 128);
                #pragma unroll
                for (int ms = 0; ms < 2; ++ms)
                    acc[ms][n3 * 3 + 0] = MFMA16(a[ms][ks], b0, acc[ms][n3 * 3 + 0]);
                #pragma unroll
                for (int ms = 0; ms < 2; ++ms)
                    acc[ms][n3 * 3 + 1] = MFMA16(a[ms][ks], b1, acc[ms][n3 * 3 + 1]);
                #pragma unroll
                for (int ms = 0; ms < 2; ++ms)
                    acc[ms][n3 * 3 + 2] = MFMA16(a[ms][ks], b2, acc[ms][n3 * 3 + 2]);
            }
            #pragma unroll
            for (int ms = 0; ms < 2; ++ms)
                a[ms][ks] = *(const short8*)(bT + aOff[ms] + ks * 32);
        }

        __syncthreads();   // all waves done reading Bs before next stage
    }

    // ---- epilogue: direct stores, out = acc + E[b][co][rc(h)][cc(w)] ----
    #pragma unroll
    for (int ms = 0; ms < 2; ++ms) {
        int p0 = pixBase + wv * 32 + ms * 16 + q * 4;  // D-layout row = q*4+reg
        int b  = p0 / HW;
        int hw0 = p0 - b * HW;                          // 4-aligned, no b straddle
        int h = hw0 / W_;
        int w0 = hw0 - h * W_;                          // 4-aligned, no row straddle
        int rc = (h == 0) ? 0 : ((h == H_ - 1) ? 2 : 1);
        int cc0 = (w0 == 0) ? 0 : ((w0 == W_ - 1) ? 2 : 1);
        int cc1 = (w0 + 1 == W_ - 1) ? 2 : 1;
        int cc2 = (w0 + 2 == W_ - 1) ? 2 : 1;
        int cc3 = (w0 + 3 == W_ - 1) ? 2 : 1;
        const float* Ebase = E + (size_t)b * COUT * 9 + rc * 3;
        float* outB = out + (size_t)b * COUT * HW + hw0;
        #pragma unroll
        for (int n = 0; n < 9; ++n) {
            int co = n * 16 + r16;                      // D-layout col = lane&15
            const float* Eb = Ebase + co * 9;
            float4 v;
            v.x = acc[ms][n][0] + Eb[cc0];
            v.y = acc[ms][n][1] + Eb[cc1];
            v.z = acc[ms][n][2] + Eb[cc2];
            v.w = acc[ms][n][3] + Eb[cc3];
            *(float4*)(outB + (size_t)co * HW) = v;
        }
    }
}

// ---------------------------------------------------------------------------
extern "C" void kernel_launch(void* const* d_in, const int* in_sizes, int n_in,
                              void* d_out, int out_size, void* d_ws, size_t ws_size,
                              hipStream_t stream) {
    const float* x     = (const float*)d_in[0];
    const float* extra = (const float*)d_in[1];
    const float* Wm    = (const float*)d_in[2];
    const float* bm    = (const float*)d_in[3];
    const float* Wx    = (const float*)d_in[4];
    const float* bx    = (const float*)d_in[5];
    float* out = (float*)d_out;

    const size_t XT_BYTES = XTP_SHORTS * 2;            // 20,668,416
    const size_t WT_BYTES = (size_t)COUT * KTOT * 2;   //    248,832
    const size_t E_BYTES  = (size_t)B_ * COUT * 9 * 4; //    165,888
    if (ws_size < XT_BYTES + WT_BYTES + E_BYTES) return;

    unsigned short* xTp = (unsigned short*)d_ws;
    unsigned short* Wt  = (unsigned short*)((char*)d_ws + XT_BYTES);
    float*          E   = (float*)((char*)d_ws + XT_BYTES + WT_BYTES);

    prep_all<<<TB + WB + EB + ZB, 256, 0, stream>>>(x, xTp, Wm, Wt, extra, Wx, bm, bx, E);
    conv_gemm<<<NPIX / MT, 256, 0, stream>>>(xTp, Wt, E, out);
}